// Round 12
// baseline (1589.546 us; speedup 1.0000x reference)
//
#include <hip/hip_runtime.h>
#include <hip/hip_bf16.h>

#define BS 64
#define SEQ 200
#define NSK 4096
#define DS 256
#define SM 64
#define NROWS (BS*SEQ)
#define AG_FR 56                          // weight frags per wave in AGPR (224 regs)
#define LDS_FR 8                          // weight frags per wave in LDS
#define LSTM_LDS (8192 + LDS_FR*8*1024)   // 8KB h + 64KB weights = 73728

typedef __attribute__((ext_vector_type(8))) short bf16x8;
typedef __attribute__((ext_vector_type(4))) float f32x4;
typedef unsigned long long u64;

__device__ __forceinline__ float sigf(float x){ return 1.0f/(1.0f+expf(-x)); }
__device__ __forceinline__ float fast_sig(float x){ return 1.0f/(1.0f+__expf(-x)); }
__device__ __forceinline__ float fast_tanh(float x){
  float t = __expf(-2.0f*fabsf(x));
  float r = (1.0f - t)/(1.0f + t);
  return copysignf(r, x);
}
__device__ __forceinline__ short f2bf(float x){
  unsigned int u = __float_as_uint(x);
  unsigned int r = (u + 0x7fffu + ((u >> 16) & 1u)) >> 16;
  return (short)r;
}
__device__ __forceinline__ float bf2f(unsigned short s){
  return __uint_as_float(((unsigned int)s) << 16);
}
// MFMA with B resident in AGPR (no accvgpr copies) / in VGPR (from LDS)
__device__ __forceinline__ void mfma_a(f32x4& acc, const bf16x8& a, const bf16x8& b){
  asm("v_mfma_f32_16x16x32_bf16 %0, %1, %2, %0" : "+v"(acc) : "v"(a), "a"(b));
}
__device__ __forceinline__ void mfma_v(f32x4& acc, const bf16x8& a, const bf16x8& b){
  asm("v_mfma_f32_16x16x32_bf16 %0, %1, %2, %0" : "+v"(acc) : "v"(a), "v"(b));
}

// ---------------- weight pre-conversion f32 -> bf16 -------------------------
__global__ __launch_bounds__(256) void k_cvtw(
    const float* __restrict__ Wa, const float* __restrict__ We,
    const float* __restrict__ Wadd, const float* __restrict__ Wf,
    const float* __restrict__ Wih, ushort* __restrict__ out)
{
  const int bid = blockIdx.x;
  const float* src; size_t rbase; int lb;
  if      (bid < 64) { src = Wa;   rbase = 0;      lb = bid; }
  else if (bid < 96) { src = We;   rbase = 131072; lb = bid - 64; }
  else if (bid < 128){ src = Wadd; rbase = 196608; lb = bid - 96; }
  else if (bid < 192){ src = Wf;   rbase = 262144; lb = bid - 128; }
  else               { src = Wih;  rbase = 393216; lb = bid - 192; }
  const int idx = (lb*256 + threadIdx.x) * 8;
  float4 a1 = *(const float4*)(src + idx);
  float4 a2 = *(const float4*)(src + idx + 4);
  bf16x8 v;
  v[0]=f2bf(a1.x); v[1]=f2bf(a1.y); v[2]=f2bf(a1.z); v[3]=f2bf(a1.w);
  v[4]=f2bf(a2.x); v[5]=f2bf(a2.y); v[6]=f2bf(a2.z); v[7]=f2bf(a2.w);
  *(bf16x8*)(out + rbase + idx) = v;
}

// ---------------- Kernel A: gather k,v + attention softmax w ----------------
__global__ __launch_bounds__(256) void k_gather_attn(
    const int* __restrict__ q, const int* __restrict__ r,
    const float* __restrict__ k_emb, const float* __restrict__ x_emb,
    const float* __restrict__ Mk,
    float* __restrict__ X2, float* __restrict__ vbuf, float* __restrict__ wbuf)
{
  __shared__ float ks[4][DS];
  const int tid = threadIdx.x;
  const int wv = tid >> 6, ln = tid & 63;
  const int row = blockIdx.x * 4 + wv;
  const int b = row / SEQ, s = row % SEQ;
  const int qi = q[b*SEQ + s];
  const int ri = r[b*SEQ + s];
  const float4* kr = (const float4*)(k_emb + (size_t)qi * DS);
  const float4* vr = (const float4*)(x_emb + ((size_t)qi + (size_t)NSK * ri) * DS);
  float4 kv = kr[ln];
  float4 vv = vr[ln];
  ((float4*)(X2 + (size_t)row*512 + DS))[ln] = kv;
  ((float4*)(vbuf + (size_t)row*DS))[ln] = vv;
  *((float4*)&ks[wv][ln*4]) = kv;
  __syncthreads();
  const float4* mkr = (const float4*)(Mk + (size_t)ln * DS);
  float a0=0.f,a1=0.f,a2=0.f,a3=0.f;
  #pragma unroll 8
  for (int d4=0; d4<DS/4; d4++){
    float4 m4 = mkr[d4];
    float4 k4 = *((const float4*)&ks[wv][d4*4]);
    a0 += m4.x*k4.x; a1 += m4.y*k4.y; a2 += m4.z*k4.z; a3 += m4.w*k4.w;
  }
  float lg = (a0+a1)+(a2+a3);
  float mx = lg;
  #pragma unroll
  for (int off=32; off; off>>=1) mx = fmaxf(mx, __shfl_xor(mx, off));
  float ex = expf(lg - mx);
  float sm = ex;
  #pragma unroll
  for (int off=32; off; off>>=1) sm += __shfl_xor(sm, off);
  wbuf[(size_t)row*SM + ln] = ex / sm;
}

// ---------------- bf16 MFMA GEMM: C = act(A @ W^T + bias [+bias2]) ----------
template<int ACT, int ABF, int OUT, int NT>
__global__ __launch_bounds__(256) void k_gemm2(
    const void* __restrict__ A0, int lda0, int K0,
    const void* __restrict__ A1, int lda1, int K1,
    const ushort* __restrict__ W, const float* __restrict__ bias,
    const float* __restrict__ bias2,
    void* __restrict__ C, int N)
{
  const int K = K0 + K1;
  __shared__ __align__(16) char As[64*80];
  __shared__ __align__(16) char Bs[NT][64*80];
  const int tid = threadIdx.x;
  const int l = tid & 63, w = tid >> 6;
  const int m0 = blockIdx.x * 64, n0 = blockIdx.y * (64*NT);
  const int mh = w >> 1, nh = w & 1;
  const int srow = tid >> 2, sseg = tid & 3;

  f32x4 acc[NT][2][2];
  #pragma unroll
  for (int nt=0; nt<NT; nt++)
    #pragma unroll
    for (int i=0;i<2;i++)
      #pragma unroll
      for (int j=0;j<2;j++) acc[nt][i][j] = (f32x4){0.f,0.f,0.f,0.f};

  for (int k0=0; k0<K; k0+=32){
    const int kk = k0 + sseg*8;
    bf16x8 av;
    if (ABF){
      const ushort* ap = (kk < K0) ? (const ushort*)A0 + (size_t)(m0+srow)*lda0 + kk
                                   : (const ushort*)A1 + (size_t)(m0+srow)*lda1 + (kk-K0);
      av = *(const bf16x8*)ap;
    } else {
      const float* ap = (kk < K0) ? (const float*)A0 + (size_t)(m0+srow)*lda0 + kk
                                  : (const float*)A1 + (size_t)(m0+srow)*lda1 + (kk-K0);
      float4 a1 = *(const float4*)ap;
      float4 a2 = *(const float4*)(ap+4);
      av[0]=f2bf(a1.x); av[1]=f2bf(a1.y); av[2]=f2bf(a1.z); av[3]=f2bf(a1.w);
      av[4]=f2bf(a2.x); av[5]=f2bf(a2.y); av[6]=f2bf(a2.z); av[7]=f2bf(a2.w);
    }
    *(bf16x8*)(As + srow*80 + ((sseg ^ (srow&3))*16)) = av;
    #pragma unroll
    for (int nt=0; nt<NT; nt++){
      bf16x8 bv = *(const bf16x8*)(W + (size_t)(n0 + nt*64 + srow)*K + kk);
      *(bf16x8*)(Bs[nt] + srow*80 + ((sseg ^ (srow&3))*16)) = bv;
    }
    __syncthreads();
    bf16x8 af[2];
    #pragma unroll
    for (int mi=0; mi<2; mi++){
      const int row = mh*32 + mi*16 + (l&15);
      af[mi] = *(const bf16x8*)(As + row*80 + (((l>>4) ^ (row&3))*16));
    }
    #pragma unroll
    for (int nt=0; nt<NT; nt++){
      bf16x8 bf[2];
      #pragma unroll
      for (int ni=0; ni<2; ni++){
        const int row = nh*32 + ni*16 + (l&15);
        bf[ni] = *(const bf16x8*)(Bs[nt] + row*80 + (((l>>4) ^ (row&3))*16));
      }
      #pragma unroll
      for (int mi=0; mi<2; mi++)
        #pragma unroll
        for (int ni=0; ni<2; ni++)
          acc[nt][mi][ni] = __builtin_amdgcn_mfma_f32_16x16x32_bf16(af[mi], bf[ni], acc[nt][mi][ni], 0,0,0);
    }
    __syncthreads();
  }
  #pragma unroll
  for (int nt=0; nt<NT; nt++){
    #pragma unroll
    for (int mi=0; mi<2; mi++){
      #pragma unroll
      for (int ni=0; ni<2; ni++){
        const int n = n0 + nt*64 + nh*32 + ni*16 + (l&15);
        float bsum = bias[n] + (bias2 ? bias2[n] : 0.f);
        #pragma unroll
        for (int j=0;j<4;j++){
          const int m = m0 + mh*32 + mi*16 + (l>>4)*4 + j;
          float v = acc[nt][mi][ni][j] + bsum;
          if (ACT==1) v = sigf(v);
          else if (ACT==2) v = tanhf(v);
          if (OUT==0)      ((float*)C)[(size_t)m*N + n] = v;
          else if (OUT==1) ((ushort*)C)[(size_t)m*N + n] = (ushort)f2bf(v);
          else             ((ushort*)C)[(size_t)m*N + ((n&255)*4 + (n>>8))] = (ushort)f2bf(v);
        }
      }
    }
  }
}

// ---------------- fused erase/add GEMM (A bf16, B pre-converted bf16) -------
__global__ __launch_bounds__(256) void k_gemm_ea(
    const ushort* __restrict__ A, const ushort* __restrict__ We_bf,
    const float* __restrict__ b_e, const ushort* __restrict__ Wadd_bf,
    const float* __restrict__ b_add,
    float* __restrict__ ebuf, float* __restrict__ abuf)
{
  __shared__ __align__(16) char As[64*80];
  __shared__ __align__(16) char Bse[64*80];
  __shared__ __align__(16) char Bsa[64*80];
  const int tid = threadIdx.x;
  const int l = tid & 63, w = tid >> 6;
  const int m0 = blockIdx.x * 64, n0 = blockIdx.y * 64;
  const int mh = w >> 1, nh = w & 1;
  const int srow = tid >> 2, sseg = tid & 3;

  f32x4 acce[2][2], acca[2][2];
  #pragma unroll
  for (int i=0;i<2;i++)
    #pragma unroll
    for (int j=0;j<2;j++){ acce[i][j]=(f32x4){0.f,0.f,0.f,0.f}; acca[i][j]=(f32x4){0.f,0.f,0.f,0.f}; }

  for (int k0=0; k0<DS; k0+=32){
    const int kk = k0 + sseg*8;
    bf16x8 av = *(const bf16x8*)(A + (size_t)(m0+srow)*DS + kk);
    *(bf16x8*)(As + srow*80 + ((sseg ^ (srow&3))*16)) = av;
    bf16x8 be = *(const bf16x8*)(We_bf + (size_t)(n0+srow)*DS + kk);
    *(bf16x8*)(Bse + srow*80 + ((sseg ^ (srow&3))*16)) = be;
    bf16x8 ba = *(const bf16x8*)(Wadd_bf + (size_t)(n0+srow)*DS + kk);
    *(bf16x8*)(Bsa + srow*80 + ((sseg ^ (srow&3))*16)) = ba;
    __syncthreads();
    bf16x8 af[2], bfe[2], bfa[2];
    #pragma unroll
    for (int mi=0; mi<2; mi++){
      const int row = mh*32 + mi*16 + (l&15);
      af[mi] = *(const bf16x8*)(As + row*80 + (((l>>4) ^ (row&3))*16));
    }
    #pragma unroll
    for (int ni=0; ni<2; ni++){
      const int row = nh*32 + ni*16 + (l&15);
      bfe[ni] = *(const bf16x8*)(Bse + row*80 + (((l>>4) ^ (row&3))*16));
      bfa[ni] = *(const bf16x8*)(Bsa + row*80 + (((l>>4) ^ (row&3))*16));
    }
    #pragma unroll
    for (int mi=0; mi<2; mi++)
      #pragma unroll
      for (int ni=0; ni<2; ni++){
        acce[mi][ni] = __builtin_amdgcn_mfma_f32_16x16x32_bf16(af[mi], bfe[ni], acce[mi][ni], 0,0,0);
        acca[mi][ni] = __builtin_amdgcn_mfma_f32_16x16x32_bf16(af[mi], bfa[ni], acca[mi][ni], 0,0,0);
      }
    __syncthreads();
  }
  #pragma unroll
  for (int mi=0; mi<2; mi++){
    #pragma unroll
    for (int ni=0; ni<2; ni++){
      const int n = n0 + nh*32 + ni*16 + (l&15);
      const float be = b_e[n], ba = b_add[n];
      #pragma unroll
      for (int j=0;j<4;j++){
        const int m = m0 + mh*32 + mi*16 + (l>>4)*4 + j;
        ebuf[(size_t)m*DS + n] = sigf(acce[mi][ni][j] + be);
        abuf[(size_t)m*DS + n] = tanhf(acca[mi][ni][j] + ba);
      }
    }
  }
}

// ---------------- Memory scan (sequential over t, next-step prefetch) -------
__global__ __launch_bounds__(256) void k_scan(
    const float* __restrict__ wbuf, const float* __restrict__ ebuf,
    const float* __restrict__ abuf, const float* __restrict__ Mv0,
    float* __restrict__ X2)
{
  const int b = blockIdx.x;
  const int d = threadIdx.x;
  __shared__ float ws[SM];
  float mem[SM];
  #pragma unroll
  for (int m=0;m<SM;m++) mem[m] = Mv0[m*DS + d];
  const size_t rb = (size_t)b*SEQ;
  float wn = (d < SM) ? wbuf[rb*SM + d] : 0.f;
  float en = ebuf[rb*DS + d];
  float an = abuf[rb*DS + d];
  for (int t=0;t<SEQ;t++){
    if (d < SM) ws[d] = wn;
    const float e = en, a = an;
    __syncthreads();
    if (t+1 < SEQ){
      wn = (d < SM) ? wbuf[(rb+t+1)*SM + d] : 0.f;
      en = ebuf[(rb+t+1)*DS + d];
      an = abuf[(rb+t+1)*DS + d];
    }
    float r0=0.f,r1=0.f,r2=0.f,r3=0.f;
    #pragma unroll
    for (int m=0;m<SM;m+=4){
      float w0=ws[m], w1=ws[m+1], w2=ws[m+2], w3=ws[m+3];
      r0 += w0*mem[m];   mem[m]   += w0*fmaf(-e, mem[m],   a);
      r1 += w1*mem[m+1]; mem[m+1] += w1*fmaf(-e, mem[m+1], a);
      r2 += w2*mem[m+2]; mem[m+2] += w2*fmaf(-e, mem[m+2], a);
      r3 += w3*mem[m+3]; mem[m+3] += w3*fmaf(-e, mem[m+3], a);
    }
    X2[(rb+t)*512 + d] = (r0+r1)+(r2+r3);
    __syncthreads();
  }
}

// ---------------- Zero-communication LSTM, AGPR-resident weights ------------
// 4 blocks x 512 threads; block g owns batches [16g,+16); full W_hh per block.
// Per wave: 64 bf16 B-frags -> 56 in AGPRs (224 regs, consumed DIRECTLY by
// inline-asm MFMA with an "a" operand -- no accvgpr copies), 8 in LDS.
// h(t-1) in 8KB swizzled LDS, read once per step. No inter-block comm.
__global__ __launch_bounds__(512) void k_lstm_nc(
    const ushort* __restrict__ gin2, const float* __restrict__ W_hh,
    const float* __restrict__ hx, const float* __restrict__ cx,
    short* __restrict__ hhist)
{
  extern __shared__ char L[];
  char* hsm  = L;                 // 8KB: 16 rows x 512B, XOR-swizzled
  char* wlds = L + 8192;          // 64KB: [(w*8+slot)*1024 + l*16]

  const int g = blockIdx.x;
  const int tid = threadIdx.x;
  const int l = tid & 63, w = tid >> 6;

  // ---- W_hh -> frags. f = (gt*2+half)*8 + kt; lane l holds W[G][k],
  // G = gt*256 + w*32 + half*16 + (l&15), k = kt*32 + (l>>4)*8 + jj
  bf16x8 wv[AG_FR];
  #pragma unroll
  for (int nt=0; nt<8; nt++){
    const int gt = nt >> 1, half = nt & 1;
    const int G = gt*256 + w*32 + half*16 + (l & 15);
    const float* wrow = W_hh + (size_t)G*256;
    #pragma unroll
    for (int kt=0; kt<8; kt++){
      const int f = nt*8 + kt;
      const int k0 = kt*32 + (l>>4)*8;
      float4 wa = *(const float4*)(wrow + k0);
      float4 wb = *(const float4*)(wrow + k0 + 4);
      bf16x8 fr;
      fr[0]=f2bf(wa.x); fr[1]=f2bf(wa.y); fr[2]=f2bf(wa.z); fr[3]=f2bf(wa.w);
      fr[4]=f2bf(wb.x); fr[5]=f2bf(wb.y); fr[6]=f2bf(wb.z); fr[7]=f2bf(wb.w);
      if (f < AG_FR) wv[f] = fr;
      else *(bf16x8*)(wlds + ((w*LDS_FR + (f - AG_FR)) << 10) + l*16) = fr;
    }
  }

  // ---- c init: lane owns (b,d) for half 0..1, j 0..3 ----
  float c_[8];
  #pragma unroll
  for (int half=0; half<2; half++){
    const float c0 = cx[w*32 + half*16 + (l & 15)];
    #pragma unroll
    for (int j=0;j<4;j++) c_[half*4+j] = c0;
  }

  // ---- stage hx into hsm ----
  if (tid < 256){
    const int row = tid >> 4, seg = tid & 15;
    #pragma unroll
    for (int u=0; u<2; u++){
      const int kb = seg*32 + u*16;
      const int d0 = kb >> 1;
      float4 ha = *(const float4*)(hx + d0);
      float4 hb = *(const float4*)(hx + d0 + 4);
      bf16x8 v;
      v[0]=f2bf(ha.x); v[1]=f2bf(ha.y); v[2]=f2bf(ha.z); v[3]=f2bf(ha.w);
      v[4]=f2bf(hb.x); v[5]=f2bf(hb.y); v[6]=f2bf(hb.z); v[7]=f2bf(hb.w);
      *(bf16x8*)(hsm + row*512 + (kb ^ ((row&7)<<4))) = v;
    }
  }
  __syncthreads();

  // running pointers
  const int b0 = g*16 + (l>>4)*4;
  const int d0 = w*32 + (l & 15);
  const char* gp = (const char*)gin2 + ((size_t)(b0*SEQ)*1024 + d0*4)*2;
  char* hp = (char*)hhist + ((size_t)(b0*SEQ)*256 + d0)*2;

  for (int t=0; t<SEQ; t++){
    // gin loads for both halves (latency hides under MFMA)
    u64 gld[8];
    #pragma unroll
    for (int half=0; half<2; half++)
      #pragma unroll
      for (int j=0;j<4;j++)
        gld[half*4+j] = *(const u64*)(gp + (size_t)j*(SEQ*2048) + half*128);

    // h fragments read ONCE (shared by both halves / all gates)
    bf16x8 a8[8];
    const int r0 = l & 15;
    #pragma unroll
    for (int kt=0; kt<8; kt++){
      const int kbyte = kt*64 + (l>>4)*16;
      a8[kt] = *(const bf16x8*)(hsm + r0*512 + (kbyte ^ ((r0&7)<<4)));
    }

    // 64 MFMA: acc[nt] for nt=(gt*2+half)
    f32x4 acc[8];
    #pragma unroll
    for (int nt=0; nt<8; nt++) acc[nt] = (f32x4){0.f,0.f,0.f,0.f};
    #pragma unroll
    for (int kt=0; kt<8; kt++){
      #pragma unroll
      for (int nt=0; nt<8; nt++){
        const int f = nt*8 + kt;
        if (f < AG_FR){
          mfma_a(acc[nt], a8[kt], wv[f]);
        } else {
          bf16x8 bfr = *(const bf16x8*)(wlds + ((w*LDS_FR + (f - AG_FR)) << 10) + l*16);
          mfma_v(acc[nt], a8[kt], bfr);
        }
      }
    }

    // gates
    ushort hh[8];
    #pragma unroll
    for (int half=0; half<2; half++){
      #pragma unroll
      for (int j=0;j<4;j++){
        const u64 gv = gld[half*4+j];
        float iv = acc[0*2+half][j] + bf2f((unsigned short)(gv       & 0xffffu));
        float fv = acc[1*2+half][j] + bf2f((unsigned short)((gv>>16) & 0xffffu));
        float gg = acc[2*2+half][j] + bf2f((unsigned short)((gv>>32) & 0xffffu));
        float ov = acc[3*2+half][j] + bf2f((unsigned short)((gv>>48) & 0xffffu));
        float cc = fast_sig(fv)*c_[half*4+j] + fast_sig(iv)*fast_tanh(gg);
        c_[half*4+j] = cc;
        float h = fast_sig(ov)*fast_tanh(cc);
        ushort hb = (ushort)f2bf(h);
        hh[half*4+j] = hb;
        *(short*)(hp + (size_t)j*(SEQ*512) + half*32) = (short)hb;
      }
    }
    gp += 2048;
    hp += 512;
    __syncthreads();   // all reads of h(t-1) complete
    #pragma unroll
    for (int half=0; half<2; half++)
      #pragma unroll
      for (int j=0;j<4;j++){
        const int b = (l>>4)*4 + j;
        const int d = w*32 + half*16 + (l & 15);
        *(short*)(hsm + b*512 + ((d*2) ^ ((b&7)<<4))) = (short)hh[half*4+j];
      }
    __syncthreads();   // h(t) staged
  }
}

// ---------------- p output: sigmoid(h . W_p + b_p) --------------------------
__global__ __launch_bounds__(256) void k_pout(
    const short* __restrict__ hhist, const float* __restrict__ W_p,
    const float* __restrict__ b_p, float* __restrict__ out)
{
  const int tid = threadIdx.x;
  const int row = blockIdx.x*4 + (tid>>6);
  const int ln = tid & 63;
  ushort4 hv = ((const ushort4*)(hhist + (size_t)row*256))[ln];
  float4 wp = ((const float4*)W_p)[ln];
  float s = bf2f(hv.x)*wp.x + bf2f(hv.y)*wp.y + bf2f(hv.z)*wp.z + bf2f(hv.w)*wp.w;
  #pragma unroll
  for (int off=32; off; off>>=1) s += __shfl_xor(s, off);
  if (ln == 0) out[row] = sigf(s + b_p[0]);
}

extern "C" void kernel_launch(void* const* d_in, const int* in_sizes, int n_in,
                              void* d_out, int out_size, void* d_ws, size_t ws_size,
                              hipStream_t stream)
{
  const int*   q     = (const int*)d_in[0];
  const int*   r     = (const int*)d_in[1];
  const float* k_emb = (const float*)d_in[2];
  const float* x_emb = (const float*)d_in[3];
  const float* Mk    = (const float*)d_in[4];
  const float* Mv0   = (const float*)d_in[5];
  const float* W_a   = (const float*)d_in[6];
  const float* b_a   = (const float*)d_in[7];
  const float* W_e   = (const float*)d_in[8];
  const float* b_e   = (const float*)d_in[9];
  const float* W_add = (const float*)d_in[10];
  const float* b_add = (const float*)d_in[11];
  const float* W_f   = (const float*)d_in[12];
  const float* b_f   = (const float*)d_in[13];
  const float* hx    = (const float*)d_in[14];
  const float* cx    = (const float*)d_in[15];
  const float* W_ih  = (const float*)d_in[16];
  const float* b_ih  = (const float*)d_in[17];
  const float* W_hh  = (const float*)d_in[18];
  const float* b_hh  = (const float*)d_in[19];
  const float* W_p   = (const float*)d_in[20];
  const float* b_p   = (const float*)d_in[21];
  float* out = (float*)d_out;

  // byte-offset workspace layout
  char* base = (char*)d_ws;
  float*  vbuf  = (float*)(base);                          // 13.1MB
  ushort* webuf = (ushort*)(base + 13107200);              // 6.55MB
  float*  ebuf  = (float*)(base + 19660800);               // 13.1MB
  float*  abuf  = (float*)(base + 32768000);               // 13.1MB
  float*  X2    = (float*)(base + 45875200);               // 26.2MB [reads|k]
  float*  wbuf  = (float*)(base + 72089600);               // 3.3MB
  ushort* fbuf  = (ushort*)(base + 75366400);              // 6.55MB
  ushort* gin2  = (ushort*)(base);                         // 26.2MB overlay (vbuf..ebuf dead)
  short*  hhist = (short*)fbuf;                            // overlay (fbuf dead post-gin)
  ushort* wbf   = (ushort*)(base + 82000000);              // 1.31MB bf16 weights

  ushort* wa_bf   = wbf;
  ushort* we_bf   = wbf + 131072;
  ushort* wadd_bf = wbf + 196608;
  ushort* wf_bf   = wbf + 262144;
  ushort* wih_bf  = wbf + 393216;

  k_cvtw<<<320, 256, 0, stream>>>(W_a, W_e, W_add, W_f, W_ih, wbf);
  k_gather_attn<<<NROWS/4, 256, 0, stream>>>(q, r, k_emb, x_emb, Mk, X2, vbuf, wbuf);
  // we = [k|v] @ W_a^T + b_a  -> bf16
  k_gemm2<0,0,1,1><<<dim3(NROWS/64, 4), 256, 0, stream>>>(X2+DS, 512, DS, vbuf, DS, DS, wa_bf, b_a, nullptr, webuf, DS);
  // erase/add fused
  k_gemm_ea<<<dim3(NROWS/64, 4), 256, 0, stream>>>(webuf, we_bf, b_e, wadd_bf, b_add, ebuf, abuf);
  // memory scan -> reads into X2[:,0:256]
  k_scan<<<BS, DS, 0, stream>>>(wbuf, ebuf, abuf, Mv0, X2);
  // f = tanh([reads|k] @ W_f^T + b_f) -> bf16
  k_gemm2<2,0,1,1><<<dim3(NROWS/64, 4), 256, 0, stream>>>(X2, 512, DS, X2+DS, 512, DS, wf_bf, b_f, nullptr, fbuf, DS);
  // gin = f @ W_ih^T + (b_ih + b_hh) -> bf16 gate-interleaved, NT=2
  k_gemm2<0,1,2,2><<<dim3(NROWS/64, 8), 256, 0, stream>>>(fbuf, DS, DS, fbuf, DS, 0, wih_bf, b_ih, b_hh, gin2, 1024);
  // zero-comm LSTM with AGPR-resident weights
  hipFuncSetAttribute((const void*)k_lstm_nc,
                      hipFuncAttributeMaxDynamicSharedMemorySize, LSTM_LDS);
  k_lstm_nc<<<4, 512, LSTM_LDS, stream>>>(gin2, W_hh, hx, cx, hhist);
  // p = sigmoid(h . W_p + b_p)
  k_pout<<<NROWS/4, 256, 0, stream>>>(hhist, W_p, b_p, out);
}